// Round 1
// baseline (2750.102 us; speedup 1.0000x reference)
//
#include <hip/hip_runtime.h>
#include <math.h>

// Problem constants
#define NB   4
#define CCH  512
#define LL   4096          // H*W = 64*64
#define GRP  32
#define CPG  16            // channels per group
#define CL   (CCH*LL)      // per-batch channel-plane stride = 2097152
#define EPSV 1e-5f

// ---------------------------------------------------------------------------
// GroupNorm: one block per (n, group). 16 ch * 4096 = 65536 elems per group.
// ---------------------------------------------------------------------------
__global__ __launch_bounds__(1024) void gn_kernel(const float* __restrict__ x,
                                                  const float* __restrict__ gamma,
                                                  const float* __restrict__ beta,
                                                  float* __restrict__ h) {
    int n = blockIdx.x >> 5;   // / GRP
    int g = blockIdx.x & 31;   // % GRP
    size_t base = ((size_t)n * CCH + (size_t)g * CPG) * LL;
    const float4* xp = (const float4*)(x + base);
    float4* hp = (float4*)(h + base);
    const int NV = CPG * LL / 4;   // 16384 float4
    int tid = threadIdx.x;

    float s1 = 0.f, s2 = 0.f;
    for (int i = tid; i < NV; i += 1024) {
        float4 v = xp[i];
        s1 += v.x + v.y + v.z + v.w;
        s2 += v.x*v.x + v.y*v.y + v.z*v.z + v.w*v.w;
    }
    __shared__ float red[32];
    for (int o = 32; o; o >>= 1) { s1 += __shfl_down(s1, o); s2 += __shfl_down(s2, o); }
    int lane = tid & 63, w = tid >> 6;
    if (lane == 0) { red[w] = s1; red[16 + w] = s2; }
    __syncthreads();
    if (tid == 0) {
        float a = 0.f, b = 0.f;
        for (int i = 0; i < 16; ++i) { a += red[i]; b += red[16 + i]; }
        red[0] = a; red[16] = b;
    }
    __syncthreads();
    const float inv_n = 1.f / (float)(CPG * LL);
    float mean = red[0] * inv_n;
    float var  = red[16] * inv_n - mean * mean;
    float rstd = rsqrtf(var + EPSV);

    for (int i = tid; i < NV; i += 1024) {
        int c = g * CPG + (i >> 10);      // (i*4)/4096
        float sc = gamma[c] * rstd;
        float bi = beta[c] - mean * sc;
        float4 v = xp[i];
        v.x = v.x * sc + bi; v.y = v.y * sc + bi;
        v.z = v.z * sc + bi; v.w = v.w * sc + bi;
        hp[i] = v;
    }
}

// ---------------------------------------------------------------------------
// Generic tiled fp32 GEMM: C[m][n] = epi( sum_k A(m,k)*B(k,n) )
// A(m,k) = A[m*lda_m + k*lda_k], B(k,n) = B[k*ldb_k + n*ldb_n], C row-major ldc.
// AKF/BKF pick the fast-moving index during tile load for coalescing.
// EPI: 0 = *alpha, 1 = +bias[m], 2 = +bias[m]+resid[m*ldc+n]
// Tiles: 64x64x16, 256 threads, 4x4 per thread.
// ---------------------------------------------------------------------------
template<int EPI, bool AKF, bool BKF>
__global__ __launch_bounds__(256) void gemm64(
    const float* __restrict__ A, const float* __restrict__ B, float* __restrict__ Cm,
    int M, int Nn, int K,
    int lda_m, int lda_k, int ldb_k, int ldb_n, int ldc,
    size_t bsA, size_t bsB, size_t bsC, size_t bsR,
    const float* __restrict__ bias, const float* __restrict__ resid, float alpha)
{
    __shared__ float As[16][68];   // +4 pad keeps float4 alignment, breaks pow2 stride
    __shared__ float Bs[16][68];

    const int tid = threadIdx.x;
    const int tx = tid & 15, ty = tid >> 4;
    const int n0 = blockIdx.x * 64;
    const int m0 = blockIdx.y * 64;

    A  += (size_t)blockIdx.z * bsA;
    B  += (size_t)blockIdx.z * bsB;
    Cm += (size_t)blockIdx.z * bsC;
    if (EPI == 2) resid += (size_t)blockIdx.z * bsR;

    float acc[4][4];
#pragma unroll
    for (int i = 0; i < 4; ++i)
#pragma unroll
        for (int j = 0; j < 4; ++j) acc[i][j] = 0.f;

    for (int k0 = 0; k0 < K; k0 += 16) {
#pragma unroll
        for (int j = 0; j < 4; ++j) {
            int e = tid + j * 256;
            int m, kk;
            if (AKF) { kk = e & 15; m = e >> 4; } else { m = e & 63; kk = e >> 6; }
            As[kk][m] = A[(size_t)(m0 + m) * lda_m + (size_t)(k0 + kk) * lda_k];
        }
#pragma unroll
        for (int j = 0; j < 4; ++j) {
            int e = tid + j * 256;
            int nn, kk;
            if (BKF) { kk = e & 15; nn = e >> 4; } else { nn = e & 63; kk = e >> 6; }
            Bs[kk][nn] = B[(size_t)(k0 + kk) * ldb_k + (size_t)(n0 + nn) * ldb_n];
        }
        __syncthreads();
#pragma unroll
        for (int kk = 0; kk < 16; ++kk) {
            float4 a4 = *reinterpret_cast<const float4*>(&As[kk][ty * 4]);
            float4 b4 = *reinterpret_cast<const float4*>(&Bs[kk][tx * 4]);
            float a[4] = {a4.x, a4.y, a4.z, a4.w};
            float b[4] = {b4.x, b4.y, b4.z, b4.w};
#pragma unroll
            for (int i = 0; i < 4; ++i)
#pragma unroll
                for (int j = 0; j < 4; ++j) acc[i][j] += a[i] * b[j];
        }
        __syncthreads();
    }

#pragma unroll
    for (int i = 0; i < 4; ++i) {
        int m = m0 + ty * 4 + i;
        float bv = (EPI >= 1) ? bias[m] : 0.f;
#pragma unroll
        for (int j = 0; j < 4; ++j) {
            int nn = n0 + tx * 4 + j;
            float v = acc[i][j];
            if (EPI == 0) v *= alpha;
            else          v += bv;
            if (EPI == 2) v += resid[(size_t)m * ldc + nn];
            Cm[(size_t)m * ldc + nn] = v;
        }
    }
}

// ---------------------------------------------------------------------------
// Row softmax over 4096 elements; one block per row, 16 elems per thread.
// ---------------------------------------------------------------------------
__global__ __launch_bounds__(256) void softmax_kernel(float* __restrict__ s) {
    float4* row = (float4*)(s + (size_t)blockIdx.x * LL);
    int tid = threadIdx.x;
    float4 v[4];
    float m = -1e30f;
#pragma unroll
    for (int j = 0; j < 4; ++j) {
        v[j] = row[tid + j * 256];
        m = fmaxf(m, fmaxf(fmaxf(v[j].x, v[j].y), fmaxf(v[j].z, v[j].w)));
    }
    __shared__ float red[16];
    for (int o = 32; o; o >>= 1) m = fmaxf(m, __shfl_down(m, o));
    int lane = tid & 63, w = tid >> 6;
    if (!lane) red[w] = m;
    __syncthreads();
    if (tid == 0) { float a = red[0]; for (int i = 1; i < 4; ++i) a = fmaxf(a, red[i]); red[0] = a; }
    __syncthreads();
    m = red[0];

    float sum = 0.f;
#pragma unroll
    for (int j = 0; j < 4; ++j) {
        v[j].x = __expf(v[j].x - m); v[j].y = __expf(v[j].y - m);
        v[j].z = __expf(v[j].z - m); v[j].w = __expf(v[j].w - m);
        sum += v[j].x + v[j].y + v[j].z + v[j].w;
    }
    __syncthreads();   // protect red[] reuse
    for (int o = 32; o; o >>= 1) sum += __shfl_down(sum, o);
    if (!lane) red[w] = sum;
    __syncthreads();
    if (tid == 0) { float a = 0.f; for (int i = 0; i < 4; ++i) a += red[i]; red[0] = a; }
    __syncthreads();
    float inv = 1.f / red[0];
#pragma unroll
    for (int j = 0; j < 4; ++j) {
        v[j].x *= inv; v[j].y *= inv; v[j].z *= inv; v[j].w *= inv;
        row[tid + j * 256] = v[j];
    }
}

// ---------------------------------------------------------------------------
extern "C" void kernel_launch(void* const* d_in, const int* in_sizes, int n_in,
                              void* d_out, int out_size, void* d_ws, size_t ws_size,
                              hipStream_t stream) {
    const float* x   = (const float*)d_in[0];
    const float* gnw = (const float*)d_in[1];
    const float* gnb = (const float*)d_in[2];
    const float* wq  = (const float*)d_in[3];
    const float* bq  = (const float*)d_in[4];
    const float* wk  = (const float*)d_in[5];
    const float* bk  = (const float*)d_in[6];
    const float* wv  = (const float*)d_in[7];
    const float* bv  = (const float*)d_in[8];
    const float* wo  = (const float*)d_in[9];
    const float* bo  = (const float*)d_in[10];
    float* out = (float*)d_out;

    // Workspace layout (floats): h/ao (reused) | q | k | v | scores(one batch)
    // total = 4*NB*CL + LL*LL floats = 192 MiB
    float* ws = (float*)d_ws;
    const size_t NCL = (size_t)NB * CL;
    float* h = ws;                 // later reused as attention output (ao)
    float* q = ws + NCL;
    float* k = ws + 2 * NCL;
    float* v = ws + 3 * NCL;
    float* s = ws + 4 * NCL;       // LL*LL floats, reused per batch

    // 1) GroupNorm
    gn_kernel<<<NB * GRP, 1024, 0, stream>>>(x, gnw, gnb, h);

    // 2) QKV projections: [512x512] @ [512x4096] per batch (grid.z = batch)
    //    A = weight row-major (k contiguous -> AKF), B = h (n contiguous)
    dim3 gproj(LL / 64, CCH / 64, NB);
    gemm64<1, true, false><<<gproj, 256, 0, stream>>>(
        wq, h, q, CCH, LL, CCH, CCH, 1, LL, 1, LL, 0, CL, CL, 0, bq, nullptr, 1.f);
    gemm64<1, true, false><<<gproj, 256, 0, stream>>>(
        wk, h, k, CCH, LL, CCH, CCH, 1, LL, 1, LL, 0, CL, CL, 0, bk, nullptr, 1.f);
    gemm64<1, true, false><<<gproj, 256, 0, stream>>>(
        wv, h, v, CCH, LL, CCH, CCH, 1, LL, 1, LL, 0, CL, CL, 0, bv, nullptr, 1.f);

    // 3) Attention per batch (scores buffer shared across batches)
    const float alpha = 1.0f / sqrtf((float)CCH);
    dim3 gsc(LL / 64, LL / 64, 1);
    dim3 gav(LL / 64, CCH / 64, 1);
    for (int n = 0; n < NB; ++n) {
        const float* qn = q + (size_t)n * CL;
        const float* kn = k + (size_t)n * CL;
        const float* vn = v + (size_t)n * CL;
        float* aon = h + (size_t)n * CL;   // overwrite h with attention output
        // scores[i][j] = alpha * sum_c q[c][i]*k[c][j]
        // A = q viewed (i,c): lda_m=1, lda_k=LL (m contiguous -> !AKF)
        gemm64<0, false, false><<<gsc, 256, 0, stream>>>(
            qn, kn, s, LL, LL, CCH, 1, LL, LL, 1, LL, 0, 0, 0, 0, nullptr, nullptr, alpha);
        softmax_kernel<<<LL, 256, 0, stream>>>(s);
        // ao[c][i] = sum_j v[c][j] * s[i][j]
        // A = v (c,j): lda_m=LL, lda_k=1 (AKF). B = s viewed (j,i): ldb_k=1, ldb_n=LL (BKF)
        gemm64<0, true, true><<<gav, 256, 0, stream>>>(
            vn, s, aon, CCH, LL, LL, LL, 1, 1, LL, LL, 0, 0, 0, 0, nullptr, nullptr, 1.f);
    }

    // 4) Output projection + bias + residual: out = wo@ao + bo + x
    gemm64<2, true, false><<<gproj, 256, 0, stream>>>(
        wo, h, out, CCH, LL, CCH, CCH, 1, LL, 1, LL, 0, CL, CL, CL, bo, x, 1.f);
}

// Round 2
// 541.516 us; speedup vs baseline: 5.0785x; 5.0785x over previous
//
#include <hip/hip_runtime.h>
#include <math.h>

#define NB   4
#define CCH  512
#define LL   4096
#define GRP  32
#define CPG  16
#define CL   (CCH*LL)
#define EPSV 1e-5f

typedef __bf16 bf16x8 __attribute__((ext_vector_type(8)));
typedef float  f32x4  __attribute__((ext_vector_type(4)));

#define GLOAD_LDS16(g, l) __builtin_amdgcn_global_load_lds( \
    (const __attribute__((address_space(1))) void*)(g),     \
    (__attribute__((address_space(3))) void*)(l), 16, 0, 0)

// ---------------------------------------------------------------------------
// GroupNorm pass 1: per (n,g) mean/rstd. 128 blocks x 1024 threads.
// ---------------------------------------------------------------------------
__global__ __launch_bounds__(1024) void gn_stats(const float* __restrict__ x,
                                                 float* __restrict__ stats) {
    int n = blockIdx.x >> 5, g = blockIdx.x & 31;
    size_t base = ((size_t)n * CCH + (size_t)g * CPG) * LL;
    const float4* xp = (const float4*)(x + base);
    const int NV = CPG * LL / 4;
    int tid = threadIdx.x;
    float s1 = 0.f, s2 = 0.f;
    for (int i = tid; i < NV; i += 1024) {
        float4 v = xp[i];
        s1 += v.x + v.y + v.z + v.w;
        s2 += v.x*v.x + v.y*v.y + v.z*v.z + v.w*v.w;
    }
    __shared__ float red[32];
    for (int o = 32; o; o >>= 1) { s1 += __shfl_down(s1, o); s2 += __shfl_down(s2, o); }
    int lane = tid & 63, w = tid >> 6;
    if (!lane) { red[w] = s1; red[16 + w] = s2; }
    __syncthreads();
    if (tid == 0) {
        float a = 0.f, b = 0.f;
        for (int i = 0; i < 16; ++i) { a += red[i]; b += red[16 + i]; }
        const float inv_n = 1.f / (float)(CPG * LL);
        float mean = a * inv_n;
        float var  = b * inv_n - mean * mean;
        stats[blockIdx.x * 2]     = mean;
        stats[blockIdx.x * 2 + 1] = rsqrtf(var + EPSV);
    }
}

// ---------------------------------------------------------------------------
// GroupNorm pass 2 + transpose: x [C,L] fp32 -> Ht [L,C] bf16.
// 64x64 tiles via LDS. grid (L/64, C/64, NB), 256 threads.
// ---------------------------------------------------------------------------
__global__ __launch_bounds__(256) void gn_norm_t(const float* __restrict__ x,
    const float* __restrict__ gamma, const float* __restrict__ beta,
    const float* __restrict__ stats, __bf16* __restrict__ Ht) {
    __shared__ float T[64][65];
    int n = blockIdx.z, c0 = blockIdx.y * 64, l0 = blockIdx.x * 64;
    int tid = threadIdx.x;
    int lx = tid & 63, py = tid >> 6;
    const float* xb = x + (size_t)n * CL;
#pragma unroll
    for (int p = 0; p < 16; ++p) {
        int cl = p * 4 + py;
        int c = c0 + cl;
        int g = c >> 4;
        float mean = stats[(n * GRP + g) * 2];
        float rstd = stats[(n * GRP + g) * 2 + 1];
        float sc = gamma[c] * rstd, bi = beta[c] - mean * sc;
        float v = xb[(size_t)c * LL + l0 + lx];
        T[lx][cl] = v * sc + bi;
    }
    __syncthreads();
    __bf16* hb = Ht + (size_t)n * CL;
#pragma unroll
    for (int p = 0; p < 16; ++p) {
        int ll = p * 4 + py;
        hb[(size_t)(l0 + ll) * CCH + c0 + lx] = (__bf16)T[ll][lx];
    }
}

// ---------------------------------------------------------------------------
// fp32 -> bf16 weight convert
// ---------------------------------------------------------------------------
__global__ __launch_bounds__(256) void tobf16(const float* __restrict__ src,
                                              __bf16* __restrict__ dst, int n) {
    int i = (blockIdx.x * 256 + threadIdx.x) * 4;
    if (i < n) {
        float4 v = *(const float4*)(src + i);
        dst[i]   = (__bf16)v.x; dst[i+1] = (__bf16)v.y;
        dst[i+2] = (__bf16)v.z; dst[i+3] = (__bf16)v.w;
    }
}

// ---------------------------------------------------------------------------
// bf16 MFMA GEMM, NT form: C(m,n) = epi( sum_k A[m*K+k] * B[n*K+k] )
// 128x128 tile, BK=32, 256 threads (4 waves, 2x2 wave grid, 64x64 per wave).
// global_load_lds width-16 staging, ds_read_b128 fragments, fp32 acc.
// EPI: 0 ->bf16, 1 +bias[n]->bf16, 2 +bias[m]->bf16, 3 *alpha->bf16,
//      4 +bias[m]+resid->fp32
// ---------------------------------------------------------------------------
#define BM 128
#define BN 128
#define BK 32

template<int EPI>
__global__ __launch_bounds__(256) void gemm_nt(
    const __bf16* __restrict__ A, const __bf16* __restrict__ B,
    void* __restrict__ Cv, int M, int N, int K,
    long bsA, long bsB, long bsC, long bsR,
    const float* __restrict__ bias, const float* __restrict__ resid, float alpha)
{
    __shared__ __align__(16) __bf16 As[BM * BK];
    __shared__ __align__(16) __bf16 Bs[BN * BK];
    const int tid = threadIdx.x;
    const int l = tid & 63, w = tid >> 6;
    const int wm = w >> 1, wn = w & 1;
    const int m0 = blockIdx.y * BM, n0 = blockIdx.x * BN;
    A += (long)blockIdx.z * bsA;
    B += (long)blockIdx.z * bsB;

    f32x4 acc[4][4];
#pragma unroll
    for (int i = 0; i < 4; ++i)
#pragma unroll
        for (int j = 0; j < 4; ++j) acc[i][j] = f32x4{0.f, 0.f, 0.f, 0.f};

    // staging addresses: lane covers 16B chunk (l&3) of row (l>>2) in a
    // 16-row wave slice; two issues cover 128 rows per operand.
    const __bf16* Ag = A + (size_t)(m0 + w * 16 + (l >> 2)) * K + (l & 3) * 8;
    const __bf16* Bg = B + (size_t)(n0 + w * 16 + (l >> 2)) * K + (l & 3) * 8;
    char* AsB = (char*)As + w * 1024;   // wave-uniform LDS base
    char* BsB = (char*)Bs + w * 1024;

    for (int k0 = 0; k0 < K; k0 += BK) {
        GLOAD_LDS16(Ag + k0,                 AsB);
        GLOAD_LDS16(Ag + k0 + (size_t)64*K,  AsB + 4096);
        GLOAD_LDS16(Bg + k0,                 BsB);
        GLOAD_LDS16(Bg + k0 + (size_t)64*K,  BsB + 4096);
        __syncthreads();
        bf16x8 ar[4], br[4];
#pragma unroll
        for (int t = 0; t < 4; ++t) {
            ar[t] = *(const bf16x8*)(As + (wm*64 + t*16 + (l & 15)) * BK + (l >> 4) * 8);
            br[t] = *(const bf16x8*)(Bs + (wn*64 + t*16 + (l & 15)) * BK + (l >> 4) * 8);
        }
#pragma unroll
        for (int ti = 0; ti < 4; ++ti)
#pragma unroll
            for (int tj = 0; tj < 4; ++tj)
                acc[ti][tj] = __builtin_amdgcn_mfma_f32_16x16x32_bf16(
                    ar[ti], br[tj], acc[ti][tj], 0, 0, 0);
        __syncthreads();
    }

    // epilogue: C/D layout col = lane&15, row = (lane>>4)*4 + reg
    const long cb = (long)blockIdx.z * bsC;
#pragma unroll
    for (int ti = 0; ti < 4; ++ti) {
#pragma unroll
        for (int r = 0; r < 4; ++r) {
            int m = m0 + wm*64 + ti*16 + (l >> 4)*4 + r;
            float bv = (EPI == 2 || EPI == 4) ? bias[m] : 0.f;
#pragma unroll
            for (int tj = 0; tj < 4; ++tj) {
                int n = n0 + wn*64 + tj*16 + (l & 15);
                float v = acc[ti][tj][r];
                if (EPI == 3) v *= alpha;
                if (EPI == 1) v += bias[n];
                if (EPI == 2 || EPI == 4) v += bv;
                if (EPI == 4) {
                    float rs = resid[(long)blockIdx.z * bsR + (size_t)m * N + n];
                    ((float*)Cv)[cb + (size_t)m * N + n] = v + rs;
                } else {
                    ((__bf16*)Cv)[cb + (size_t)m * N + n] = (__bf16)v;
                }
            }
        }
    }
}

// ---------------------------------------------------------------------------
// Row softmax over 4096 bf16, in place. One block (256 thr) per row.
// ---------------------------------------------------------------------------
__global__ __launch_bounds__(256) void softmax_bf16(__bf16* __restrict__ S) {
    __bf16* row = S + (size_t)blockIdx.x * LL;
    int tid = threadIdx.x;
    bf16x8 v0 = *(const bf16x8*)(row + tid * 8);
    bf16x8 v1 = *(const bf16x8*)(row + 2048 + tid * 8);
    float f[16];
#pragma unroll
    for (int i = 0; i < 8; ++i) { f[i] = (float)v0[i]; f[8 + i] = (float)v1[i]; }
    float m = -1e30f;
#pragma unroll
    for (int i = 0; i < 16; ++i) m = fmaxf(m, f[i]);
    __shared__ float red[8];
    int lane = tid & 63, w = tid >> 6;
    for (int o = 32; o; o >>= 1) m = fmaxf(m, __shfl_down(m, o));
    if (!lane) red[w] = m;
    __syncthreads();
    m = fmaxf(fmaxf(red[0], red[1]), fmaxf(red[2], red[3]));
    float sum = 0.f;
#pragma unroll
    for (int i = 0; i < 16; ++i) { f[i] = __expf(f[i] - m); sum += f[i]; }
    for (int o = 32; o; o >>= 1) sum += __shfl_down(sum, o);
    if (!lane) red[4 + w] = sum;
    __syncthreads();
    float inv = 1.f / (red[4] + red[5] + red[6] + red[7]);
#pragma unroll
    for (int i = 0; i < 8; ++i) { v0[i] = (__bf16)(f[i] * inv); v1[i] = (__bf16)(f[8+i] * inv); }
    *(bf16x8*)(row + tid * 8) = v0;
    *(bf16x8*)(row + 2048 + tid * 8) = v1;
}

// ---------------------------------------------------------------------------
extern "C" void kernel_launch(void* const* d_in, const int* in_sizes, int n_in,
                              void* d_out, int out_size, void* d_ws, size_t ws_size,
                              hipStream_t stream) {
    const float* x   = (const float*)d_in[0];
    const float* gnw = (const float*)d_in[1];
    const float* gnb = (const float*)d_in[2];
    const float* wq  = (const float*)d_in[3];
    const float* bq  = (const float*)d_in[4];
    const float* wk  = (const float*)d_in[5];
    const float* bk  = (const float*)d_in[6];
    const float* wv  = (const float*)d_in[7];
    const float* bv  = (const float*)d_in[8];
    const float* wo  = (const float*)d_in[9];
    const float* bo  = (const float*)d_in[10];
    float* out = (float*)d_out;

    // ws (bf16 units): Ht | Qt | Kt | V | Ot | S(2 batches) | Wb(4) | stats
    // 5*16MiB + 64MiB + 2MiB + 1KiB = 153 MiB
    __bf16* wsb = (__bf16*)d_ws;
    const size_t NCL = (size_t)NB * CL;
    __bf16* Ht = wsb;
    __bf16* Qt = Ht + NCL;
    __bf16* Kt = Qt + NCL;
    __bf16* Vb = Kt + NCL;
    __bf16* Ot = Vb + NCL;
    __bf16* S  = Ot + NCL;                       // 2 * LL * LL
    __bf16* Wb = S + (size_t)2 * LL * LL;        // 4 * 512 * 512
    float* stats = (float*)(Wb + (size_t)4 * CCH * CCH);
    __bf16* wqb = Wb;
    __bf16* wkb = Wb + (size_t)CCH * CCH;
    __bf16* wvb = Wb + (size_t)2 * CCH * CCH;
    __bf16* wob = Wb + (size_t)3 * CCH * CCH;

    tobf16<<<256, 256, 0, stream>>>(wq, wqb, CCH * CCH);
    tobf16<<<256, 256, 0, stream>>>(wk, wkb, CCH * CCH);
    tobf16<<<256, 256, 0, stream>>>(wv, wvb, CCH * CCH);
    tobf16<<<256, 256, 0, stream>>>(wo, wob, CCH * CCH);

    gn_stats<<<NB * GRP, 1024, 0, stream>>>(x, stats);
    gn_norm_t<<<dim3(LL / 64, CCH / 64, NB), 256, 0, stream>>>(x, gnw, gnb, stats, Ht);

    // Qt[l][d] = Ht·Wq^T + bq  (M=L, N=C, K=C), bias over n
    gemm_nt<1><<<dim3(CCH / 128, LL / 128, NB), 256, 0, stream>>>(
        Ht, wqb, Qt, LL, CCH, CCH, CL, 0, CL, 0, bq, nullptr, 1.f);
    gemm_nt<1><<<dim3(CCH / 128, LL / 128, NB), 256, 0, stream>>>(
        Ht, wkb, Kt, LL, CCH, CCH, CL, 0, CL, 0, bk, nullptr, 1.f);
    // V[d][l] = Wv·Ht^T + bv  (M=C, N=L, K=C), bias over m
    gemm_nt<2><<<dim3(LL / 128, CCH / 128, NB), 256, 0, stream>>>(
        wvb, Ht, Vb, CCH, LL, CCH, 0, CL, CL, 0, bv, nullptr, 1.f);

    const float alpha = 1.f / sqrtf((float)CCH);
    for (int p = 0; p < 2; ++p) {
        __bf16* Qp = Qt + (size_t)p * 2 * CL;
        __bf16* Kp = Kt + (size_t)p * 2 * CL;
        __bf16* Vp = Vb + (size_t)p * 2 * CL;
        __bf16* Op = Ot + (size_t)p * 2 * CL;
        // S[i][j] = alpha * Qt·Kt^T  (M=N=L, K=C)
        gemm_nt<3><<<dim3(LL / 128, LL / 128, 2), 256, 0, stream>>>(
            Qp, Kp, S, LL, LL, CCH, CL, CL, (long)LL * LL, 0, nullptr, nullptr, alpha);
        softmax_bf16<<<2 * LL, 256, 0, stream>>>(S);
        // Ot[i][c] = P·V^T  (M=L, N=C, K=L)
        gemm_nt<0><<<dim3(CCH / 128, LL / 128, 2), 256, 0, stream>>>(
            S, Vp, Op, LL, CCH, LL, (long)LL * LL, CL, CL, 0, nullptr, nullptr, 1.f);
    }

    // out[d][l] = Wo·Ot^T + bo + x  (M=C, N=L, K=C), fp32 out
    gemm_nt<4><<<dim3(LL / 128, CCH / 128, NB), 256, 0, stream>>>(
        wob, Ot, (void*)out, CCH, LL, CCH, 0, CL, CL, CL, bo, x, 1.f);
}

// Round 3
// 513.364 us; speedup vs baseline: 5.3570x; 1.0548x over previous
//
#include <hip/hip_runtime.h>
#include <math.h>

#define NB   4
#define CCH  512
#define LL   4096
#define GRP  32
#define CPG  16
#define CL   (CCH*LL)
#define EPSV 1e-5f

typedef __bf16 bf16x8 __attribute__((ext_vector_type(8)));
typedef float  f32x4  __attribute__((ext_vector_type(4)));

#define GLOAD_LDS16(g, l) __builtin_amdgcn_global_load_lds( \
    (const __attribute__((address_space(1))) void*)(g),     \
    (__attribute__((address_space(3))) void*)(l), 16, 0, 0)

// ---------------------------------------------------------------------------
// GroupNorm pass 1: per (n,g) mean/rstd. 128 blocks x 1024 threads.
// ---------------------------------------------------------------------------
__global__ __launch_bounds__(1024) void gn_stats(const float* __restrict__ x,
                                                 float* __restrict__ stats) {
    int n = blockIdx.x >> 5, g = blockIdx.x & 31;
    size_t base = ((size_t)n * CCH + (size_t)g * CPG) * LL;
    const float4* xp = (const float4*)(x + base);
    const int NV = CPG * LL / 4;
    int tid = threadIdx.x;
    float s1 = 0.f, s2 = 0.f;
    for (int i = tid; i < NV; i += 1024) {
        float4 v = xp[i];
        s1 += v.x + v.y + v.z + v.w;
        s2 += v.x*v.x + v.y*v.y + v.z*v.z + v.w*v.w;
    }
    __shared__ float red[32];
    for (int o = 32; o; o >>= 1) { s1 += __shfl_down(s1, o); s2 += __shfl_down(s2, o); }
    int lane = tid & 63, w = tid >> 6;
    if (!lane) { red[w] = s1; red[16 + w] = s2; }
    __syncthreads();
    if (tid == 0) {
        float a = 0.f, b = 0.f;
        for (int i = 0; i < 16; ++i) { a += red[i]; b += red[16 + i]; }
        const float inv_n = 1.f / (float)(CPG * LL);
        float mean = a * inv_n;
        float var  = b * inv_n - mean * mean;
        stats[blockIdx.x * 2]     = mean;
        stats[blockIdx.x * 2 + 1] = rsqrtf(var + EPSV);
    }
}

// ---------------------------------------------------------------------------
// GroupNorm pass 2 + transpose: x [C,L] fp32 -> Ht [L,C] bf16.
// ---------------------------------------------------------------------------
__global__ __launch_bounds__(256) void gn_norm_t(const float* __restrict__ x,
    const float* __restrict__ gamma, const float* __restrict__ beta,
    const float* __restrict__ stats, __bf16* __restrict__ Ht) {
    __shared__ float T[64][65];
    int n = blockIdx.z, c0 = blockIdx.y * 64, l0 = blockIdx.x * 64;
    int tid = threadIdx.x;
    int lx = tid & 63, py = tid >> 6;
    const float* xb = x + (size_t)n * CL;
#pragma unroll
    for (int p = 0; p < 16; ++p) {
        int cl = p * 4 + py;
        int c = c0 + cl;
        int g = c >> 4;
        float mean = stats[(n * GRP + g) * 2];
        float rstd = stats[(n * GRP + g) * 2 + 1];
        float sc = gamma[c] * rstd, bi = beta[c] - mean * sc;
        float v = xb[(size_t)c * LL + l0 + lx];
        T[lx][cl] = v * sc + bi;
    }
    __syncthreads();
    __bf16* hb = Ht + (size_t)n * CL;
#pragma unroll
    for (int p = 0; p < 16; ++p) {
        int ll = p * 4 + py;
        hb[(size_t)(l0 + ll) * CCH + c0 + lx] = (__bf16)T[ll][lx];
    }
}

// ---------------------------------------------------------------------------
__global__ __launch_bounds__(256) void tobf16(const float* __restrict__ src,
                                              __bf16* __restrict__ dst, int n) {
    int i = (blockIdx.x * 256 + threadIdx.x) * 4;
    if (i < n) {
        float4 v = *(const float4*)(src + i);
        dst[i]   = (__bf16)v.x; dst[i+1] = (__bf16)v.y;
        dst[i+2] = (__bf16)v.z; dst[i+3] = (__bf16)v.w;
    }
}

// ---------------------------------------------------------------------------
// bf16 MFMA GEMM, NT form (unchanged, verified round 1).
// EPI: 1 +bias[n]->bf16, 2 +bias[m]->bf16, 4 +bias[m]+resid->fp32
// ---------------------------------------------------------------------------
#define BM 128
#define BN 128
#define BK 32

template<int EPI>
__global__ __launch_bounds__(256) void gemm_nt(
    const __bf16* __restrict__ A, const __bf16* __restrict__ B,
    void* __restrict__ Cv, int M, int N, int K,
    long bsA, long bsB, long bsC, long bsR,
    const float* __restrict__ bias, const float* __restrict__ resid, float alpha)
{
    __shared__ __align__(16) __bf16 As[BM * BK];
    __shared__ __align__(16) __bf16 Bs[BN * BK];
    const int tid = threadIdx.x;
    const int l = tid & 63, w = tid >> 6;
    const int wm = w >> 1, wn = w & 1;
    const int m0 = blockIdx.y * BM, n0 = blockIdx.x * BN;
    A += (long)blockIdx.z * bsA;
    B += (long)blockIdx.z * bsB;

    f32x4 acc[4][4];
#pragma unroll
    for (int i = 0; i < 4; ++i)
#pragma unroll
        for (int j = 0; j < 4; ++j) acc[i][j] = f32x4{0.f, 0.f, 0.f, 0.f};

    const __bf16* Ag = A + (size_t)(m0 + w * 16 + (l >> 2)) * K + (l & 3) * 8;
    const __bf16* Bg = B + (size_t)(n0 + w * 16 + (l >> 2)) * K + (l & 3) * 8;
    char* AsB = (char*)As + w * 1024;
    char* BsB = (char*)Bs + w * 1024;

    for (int k0 = 0; k0 < K; k0 += BK) {
        GLOAD_LDS16(Ag + k0,                 AsB);
        GLOAD_LDS16(Ag + k0 + (size_t)64*K,  AsB + 4096);
        GLOAD_LDS16(Bg + k0,                 BsB);
        GLOAD_LDS16(Bg + k0 + (size_t)64*K,  BsB + 4096);
        __syncthreads();
        bf16x8 ar[4], br[4];
#pragma unroll
        for (int t = 0; t < 4; ++t) {
            ar[t] = *(const bf16x8*)(As + (wm*64 + t*16 + (l & 15)) * BK + (l >> 4) * 8);
            br[t] = *(const bf16x8*)(Bs + (wn*64 + t*16 + (l & 15)) * BK + (l >> 4) * 8);
        }
#pragma unroll
        for (int ti = 0; ti < 4; ++ti)
#pragma unroll
            for (int tj = 0; tj < 4; ++tj)
                acc[ti][tj] = __builtin_amdgcn_mfma_f32_16x16x32_bf16(
                    ar[ti], br[tj], acc[ti][tj], 0, 0, 0);
        __syncthreads();
    }

    const long cb = (long)blockIdx.z * bsC;
#pragma unroll
    for (int ti = 0; ti < 4; ++ti) {
#pragma unroll
        for (int r = 0; r < 4; ++r) {
            int m = m0 + wm*64 + ti*16 + (l >> 4)*4 + r;
            float bv = (EPI == 2 || EPI == 4) ? bias[m] : 0.f;
#pragma unroll
            for (int tj = 0; tj < 4; ++tj) {
                int n = n0 + wn*64 + tj*16 + (l & 15);
                float v = acc[ti][tj][r];
                if (EPI == 1) v += bias[n];
                if (EPI == 2 || EPI == 4) v += bv;
                if (EPI == 4) {
                    float rs = resid[(long)blockIdx.z * bsR + (size_t)m * N + n];
                    ((float*)Cv)[cb + (size_t)m * N + n] = v + rs;
                } else {
                    ((__bf16*)Cv)[cb + (size_t)m * N + n] = (__bf16)v;
                }
            }
        }
    }
}

// ---------------------------------------------------------------------------
// Flash attention: one block = 64 q-rows of one batch. 256 threads, 4 waves.
// Q (64x512) in registers (per-wave A-frags). Per j-tile (64 keys):
//   S = alpha*Q.K^T (MFMA, K from LDS) -> online softmax (fp32 regs)
//   -> P to LDS (bf16, padded) -> O += P.V^T (MFMA, V from LDS).
// Pipeline: V(t) staged during S(t); K(t+1) staged during PV(t).
// ---------------------------------------------------------------------------
#define PSTR 88   // P row stride (elems): 176 B, 16B-aligned, 2-way banks

__global__ __launch_bounds__(256, 1) void flash_attn(
    const __bf16* __restrict__ Qt, const __bf16* __restrict__ Kt,
    const __bf16* __restrict__ Vb, __bf16* __restrict__ Ot)
{
    __shared__ __align__(16) __bf16 Ks[16 * 64 * 32];   // [kc][j:64][k:32] 64 KB
    __shared__ __align__(16) __bf16 Vs[2 * 512 * 32];   // [jc][c:512][j:32] 64 KB
    __shared__ __align__(16) __bf16 Ps[64 * PSTR];      // 11 KB
    __shared__ float scl[64];
    __shared__ float lnv[64];

    const int tid = threadIdx.x;
    const int l = tid & 63, w = tid >> 6;
    const int b = blockIdx.x >> 6;
    const int i0 = (blockIdx.x & 63) * 64;
    const size_t bb = (size_t)b * CL;
    const float alpha = 0.044194173824159216f;  // 1/sqrt(512)

    // Q fragments: wave w owns q-rows [i0+w*16, i0+w*16+16)
    bf16x8 Qf[16];
    {
        const __bf16* Qg = Qt + bb + (size_t)(i0 + w*16 + (l & 15)) * CCH + (l >> 4) * 8;
#pragma unroll
        for (int kc = 0; kc < 16; ++kc) Qf[kc] = *(const bf16x8*)(Qg + kc * 32);
    }

    f32x4 Oacc[4][8];
#pragma unroll
    for (int mi = 0; mi < 4; ++mi)
#pragma unroll
        for (int ni = 0; ni < 8; ++ni) Oacc[mi][ni] = f32x4{0.f, 0.f, 0.f, 0.f};
    float m_r[4], l_r[4];
#pragma unroll
    for (int r = 0; r < 4; ++r) { m_r[r] = -1e30f; l_r[r] = 0.f; }

    const __bf16* Kb = Kt + bb;
    const __bf16* Vg = Vb + bb;

    // K staging: 16 sub-chunks [64][32]; wave w stages kc = {w, w+4, w+8, w+12}
    auto stageK = [&](int j0) {
#pragma unroll
        for (int q = 0; q < 4; ++q) {
            int kc = q * 4 + w;
#pragma unroll
            for (int p = 0; p < 4; ++p) {
                const __bf16* src = Kb + (size_t)(j0 + p*16 + (l >> 2)) * CCH + kc*32 + (l & 3)*8;
                GLOAD_LDS16(src, (char*)Ks + kc*4096 + p*1024);
            }
        }
    };
    // V staging: [jc][512][32]; wave w stages c-rows [w*128, w*128+128)
    auto stageV = [&](int j0) {
#pragma unroll
        for (int jc = 0; jc < 2; ++jc)
#pragma unroll
            for (int p = 0; p < 8; ++p) {
                const __bf16* src = Vg + (size_t)(w*128 + p*16 + (l >> 2)) * LL + j0 + jc*32 + (l & 3)*8;
                GLOAD_LDS16(src, (char*)Vs + jc*32768 + (w*128 + p*16)*64);
            }
    };

    stageK(0);
    for (int t = 0; t < 64; ++t) {
        __syncthreads();             // K(t) staged (drain); PV(t-1) done
        stageV(t * 64);              // overlaps S-compute; drains at next barrier

        // S = Q . K^T  (wave's 16 rows x 64 j)
        f32x4 S[4];
#pragma unroll
        for (int tj = 0; tj < 4; ++tj) S[tj] = f32x4{0.f, 0.f, 0.f, 0.f};
#pragma unroll
        for (int kc = 0; kc < 16; ++kc) {
#pragma unroll
            for (int tj = 0; tj < 4; ++tj) {
                bf16x8 kf = *(const bf16x8*)(Ks + kc*2048 + (tj*16 + (l & 15))*32 + (l >> 4)*8);
                S[tj] = __builtin_amdgcn_mfma_f32_16x16x32_bf16(Qf[kc], kf, S[tj], 0, 0, 0);
            }
        }

        // online softmax; C-layout: row = w*16 + (l>>4)*4 + r, col = tj*16 + (l&15)
#pragma unroll
        for (int r = 0; r < 4; ++r) {
            float mt = -1e30f;
#pragma unroll
            for (int tj = 0; tj < 4; ++tj) { S[tj][r] *= alpha; mt = fmaxf(mt, S[tj][r]); }
#pragma unroll
            for (int off = 1; off < 16; off <<= 1) mt = fmaxf(mt, __shfl_xor(mt, off));
            float mn = fmaxf(m_r[r], mt);
            float a = __expf(m_r[r] - mn);
            m_r[r] = mn;
            int row = w*16 + (l >> 4)*4 + r;
            float rs = 0.f;
#pragma unroll
            for (int tj = 0; tj < 4; ++tj) {
                float p = __expf(S[tj][r] - mn);
                rs += p;
                Ps[row * PSTR + tj*16 + (l & 15)] = (__bf16)p;
            }
#pragma unroll
            for (int off = 1; off < 16; off <<= 1) rs += __shfl_xor(rs, off);
            l_r[r] = l_r[r] * a + rs;
            if ((l & 15) == 0) scl[row] = a;
        }

        __syncthreads();             // P + scl visible; V(t) staged (drain)
        if (t < 63) stageK((t + 1) * 64);   // overlaps PV; drains at loop-top barrier

        // rescale O by per-row alpha
#pragma unroll
        for (int mi = 0; mi < 4; ++mi)
#pragma unroll
            for (int r = 0; r < 4; ++r) {
                float s = scl[mi*16 + (l >> 4)*4 + r];
#pragma unroll
                for (int ni = 0; ni < 8; ++ni) Oacc[mi][ni][r] *= s;
            }

        // O += P . V^T   (M=64 i, N=512 c; wave owns c-slice [w*128, w*128+128))
#pragma unroll
        for (int jc = 0; jc < 2; ++jc) {
            bf16x8 pa[4];
#pragma unroll
            for (int mi = 0; mi < 4; ++mi)
                pa[mi] = *(const bf16x8*)(Ps + (mi*16 + (l & 15)) * PSTR + jc*32 + (l >> 4)*8);
#pragma unroll
            for (int ni = 0; ni < 8; ++ni) {
                bf16x8 vf = *(const bf16x8*)(Vs + jc*16384 + (w*128 + ni*16 + (l & 15))*32 + (l >> 4)*8);
#pragma unroll
                for (int mi = 0; mi < 4; ++mi)
                    Oacc[mi][ni] = __builtin_amdgcn_mfma_f32_16x16x32_bf16(pa[mi], vf, Oacc[mi][ni], 0, 0, 0);
            }
        }
    }

    // epilogue: O /= l, store Ot[i][c] bf16
    if ((l & 15) == 0) {
#pragma unroll
        for (int r = 0; r < 4; ++r) lnv[w*16 + (l >> 4)*4 + r] = 1.f / l_r[r];
    }
    __syncthreads();
#pragma unroll
    for (int mi = 0; mi < 4; ++mi) {
#pragma unroll
        for (int r = 0; r < 4; ++r) {
            int i = i0 + mi*16 + (l >> 4)*4 + r;
            float inv = lnv[mi*16 + (l >> 4)*4 + r];
#pragma unroll
            for (int ni = 0; ni < 8; ++ni) {
                int c = w*128 + ni*16 + (l & 15);
                Ot[bb + (size_t)i * CCH + c] = (__bf16)(Oacc[mi][ni][r] * inv);
            }
        }
    }
}

// ---------------------------------------------------------------------------
extern "C" void kernel_launch(void* const* d_in, const int* in_sizes, int n_in,
                              void* d_out, int out_size, void* d_ws, size_t ws_size,
                              hipStream_t stream) {
    const float* x   = (const float*)d_in[0];
    const float* gnw = (const float*)d_in[1];
    const float* gnb = (const float*)d_in[2];
    const float* wq  = (const float*)d_in[3];
    const float* bq  = (const float*)d_in[4];
    const float* wk  = (const float*)d_in[5];
    const float* bk  = (const float*)d_in[6];
    const float* wv  = (const float*)d_in[7];
    const float* bv  = (const float*)d_in[8];
    const float* wo  = (const float*)d_in[9];
    const float* bo  = (const float*)d_in[10];
    float* out = (float*)d_out;

    // ws (bf16): Ht | Qt | Kt | V | Ot | Wb(4) | stats  = ~82 MiB
    __bf16* wsb = (__bf16*)d_ws;
    const size_t NCL = (size_t)NB * CL;
    __bf16* Ht = wsb;
    __bf16* Qt = Ht + NCL;
    __bf16* Kt = Qt + NCL;
    __bf16* Vb = Kt + NCL;
    __bf16* Ot = Vb + NCL;
    __bf16* Wb = Ot + NCL;
    float* stats = (float*)(Wb + (size_t)4 * CCH * CCH);
    __bf16* wqb = Wb;
    __bf16* wkb = Wb + (size_t)CCH * CCH;
    __bf16* wvb = Wb + (size_t)2 * CCH * CCH;
    __bf16* wob = Wb + (size_t)3 * CCH * CCH;

    tobf16<<<256, 256, 0, stream>>>(wq, wqb, CCH * CCH);
    tobf16<<<256, 256, 0, stream>>>(wk, wkb, CCH * CCH);
    tobf16<<<256, 256, 0, stream>>>(wv, wvb, CCH * CCH);
    tobf16<<<256, 256, 0, stream>>>(wo, wob, CCH * CCH);

    gn_stats<<<NB * GRP, 1024, 0, stream>>>(x, stats);
    gn_norm_t<<<dim3(LL / 64, CCH / 64, NB), 256, 0, stream>>>(x, gnw, gnb, stats, Ht);

    // Qt[l][d] = Ht.Wq^T + bq ; Kt same ; V[d][l] = Wv.Ht^T + bv
    gemm_nt<1><<<dim3(CCH / 128, LL / 128, NB), 256, 0, stream>>>(
        Ht, wqb, Qt, LL, CCH, CCH, CL, 0, CL, 0, bq, nullptr, 1.f);
    gemm_nt<1><<<dim3(CCH / 128, LL / 128, NB), 256, 0, stream>>>(
        Ht, wkb, Kt, LL, CCH, CCH, CL, 0, CL, 0, bk, nullptr, 1.f);
    gemm_nt<2><<<dim3(LL / 128, CCH / 128, NB), 256, 0, stream>>>(
        wvb, Ht, Vb, CCH, LL, CCH, 0, CL, CL, 0, bv, nullptr, 1.f);

    // fused attention: Ot[l][c]
    flash_attn<<<dim3(NB * (LL / 64)), 256, 0, stream>>>(Qt, Kt, Vb, Ot);

    // out[d][l] = Wo.Ot^T + bo + x  (fp32 out)
    gemm_nt<4><<<dim3(LL / 128, CCH / 128, NB), 256, 0, stream>>>(
        wob, Ot, (void*)out, CCH, LL, CCH, 0, CL, CL, CL, bo, x, 1.f);
}

// Round 4
// 470.747 us; speedup vs baseline: 5.8420x; 1.0905x over previous
//
#include <hip/hip_runtime.h>
#include <math.h>

#define NB   4
#define CCH  512
#define LL   4096
#define GRP  32
#define CPG  16
#define CL   (CCH*LL)
#define EPSV 1e-5f

typedef __bf16 bf16x8 __attribute__((ext_vector_type(8)));
typedef float  f32x4  __attribute__((ext_vector_type(4)));

#define GLOAD_LDS16(g, l) __builtin_amdgcn_global_load_lds( \
    (const __attribute__((address_space(1))) void*)(g),     \
    (__attribute__((address_space(3))) void*)(l), 16, 0, 0)

// ---------------------------------------------------------------------------
// XOR-swizzle for 16-row x 64B LDS tiles staged via global_load_lds.
// Stored slot for (row, 16B-chunk q): spreads fragment reads (16 rows, fixed
// q) across all 8 four-bank groups -> 2-way (free) instead of 8-way.
// ---------------------------------------------------------------------------
__device__ __forceinline__ int swz_slot(int row, int q) {
    return (4 * row + (q ^ (row & 3))) ^ (((row >> 2) & 1) << 2);
}
// Inverse: lane l stages the (row jj, chunk cc) that belongs at slot l.
__device__ __forceinline__ void swz_src(int l, int& jj, int& cc) {
    jj = ((l >> 3) << 1) | (((l >> 2) ^ (l >> 4)) & 1);
    cc = (l & 3) ^ (jj & 3);
}

// DPP 16-lane reductions (quad_perm xor1/xor2, row_ror 4/8) — VALU-speed.
#define DPPF(x, ctrl) __builtin_bit_cast(float, \
    __builtin_amdgcn_update_dpp(0, __builtin_bit_cast(int, (x)), (ctrl), 0xf, 0xf, false))
__device__ __forceinline__ float red_max16(float x) {
    x = fmaxf(x, DPPF(x, 0xB1)); x = fmaxf(x, DPPF(x, 0x4E));
    x = fmaxf(x, DPPF(x, 0x124)); x = fmaxf(x, DPPF(x, 0x128));
    return x;
}
__device__ __forceinline__ float red_sum16(float x) {
    x += DPPF(x, 0xB1); x += DPPF(x, 0x4E);
    x += DPPF(x, 0x124); x += DPPF(x, 0x128);
    return x;
}

// ---------------------------------------------------------------------------
// GroupNorm pass 1: per (n,g) mean/rstd.
// ---------------------------------------------------------------------------
__global__ __launch_bounds__(1024) void gn_stats(const float* __restrict__ x,
                                                 float* __restrict__ stats) {
    int n = blockIdx.x >> 5, g = blockIdx.x & 31;
    size_t base = ((size_t)n * CCH + (size_t)g * CPG) * LL;
    const float4* xp = (const float4*)(x + base);
    const int NV = CPG * LL / 4;
    int tid = threadIdx.x;
    float s1 = 0.f, s2 = 0.f;
    for (int i = tid; i < NV; i += 1024) {
        float4 v = xp[i];
        s1 += v.x + v.y + v.z + v.w;
        s2 += v.x*v.x + v.y*v.y + v.z*v.z + v.w*v.w;
    }
    __shared__ float red[32];
    for (int o = 32; o; o >>= 1) { s1 += __shfl_down(s1, o); s2 += __shfl_down(s2, o); }
    int lane = tid & 63, w = tid >> 6;
    if (!lane) { red[w] = s1; red[16 + w] = s2; }
    __syncthreads();
    if (tid == 0) {
        float a = 0.f, b = 0.f;
        for (int i = 0; i < 16; ++i) { a += red[i]; b += red[16 + i]; }
        const float inv_n = 1.f / (float)(CPG * LL);
        float mean = a * inv_n;
        float var  = b * inv_n - mean * mean;
        stats[blockIdx.x * 2]     = mean;
        stats[blockIdx.x * 2 + 1] = rsqrtf(var + EPSV);
    }
}

// ---------------------------------------------------------------------------
// GroupNorm pass 2 + transpose: x [C,L] fp32 -> Ht [L,C] bf16.
// ---------------------------------------------------------------------------
__global__ __launch_bounds__(256) void gn_norm_t(const float* __restrict__ x,
    const float* __restrict__ gamma, const float* __restrict__ beta,
    const float* __restrict__ stats, __bf16* __restrict__ Ht) {
    __shared__ float T[64][65];
    int n = blockIdx.z, c0 = blockIdx.y * 64, l0 = blockIdx.x * 64;
    int tid = threadIdx.x;
    int lx = tid & 63, py = tid >> 6;
    const float* xb = x + (size_t)n * CL;
#pragma unroll
    for (int p = 0; p < 16; ++p) {
        int cl = p * 4 + py;
        int c = c0 + cl;
        int g = c >> 4;
        float mean = stats[(n * GRP + g) * 2];
        float rstd = stats[(n * GRP + g) * 2 + 1];
        float sc = gamma[c] * rstd, bi = beta[c] - mean * sc;
        float v = xb[(size_t)c * LL + l0 + lx];
        T[lx][cl] = v * sc + bi;
    }
    __syncthreads();
    __bf16* hb = Ht + (size_t)n * CL;
#pragma unroll
    for (int p = 0; p < 16; ++p) {
        int ll = p * 4 + py;
        hb[(size_t)(l0 + ll) * CCH + c0 + lx] = (__bf16)T[ll][lx];
    }
}

// ---------------------------------------------------------------------------
__global__ __launch_bounds__(256) void tobf16(const float* __restrict__ src,
                                              __bf16* __restrict__ dst, int n) {
    int i = (blockIdx.x * 256 + threadIdx.x) * 4;
    if (i < n) {
        float4 v = *(const float4*)(src + i);
        dst[i]   = (__bf16)v.x; dst[i+1] = (__bf16)v.y;
        dst[i+2] = (__bf16)v.z; dst[i+3] = (__bf16)v.w;
    }
}

// ---------------------------------------------------------------------------
// bf16 MFMA GEMM, NT form, swizzled LDS.
// EPI: 1 +bias[n]->bf16, 2 +bias[m]->bf16, 4 +bias[m]+resid->fp32
// ---------------------------------------------------------------------------
#define BM 128
#define BN 128
#define BK 32

template<int EPI>
__global__ __launch_bounds__(256) void gemm_nt(
    const __bf16* __restrict__ A, const __bf16* __restrict__ B,
    void* __restrict__ Cv, int M, int N, int K,
    long bsA, long bsB, long bsC, long bsR,
    const float* __restrict__ bias, const float* __restrict__ resid, float alpha)
{
    __shared__ __align__(16) __bf16 As[BM * BK];
    __shared__ __align__(16) __bf16 Bs[BN * BK];
    const int tid = threadIdx.x;
    const int l = tid & 63, w = tid >> 6;
    const int wm = w >> 1, wn = w & 1;
    const int m0 = blockIdx.y * BM, n0 = blockIdx.x * BN;
    A += (long)blockIdx.z * bsA;
    B += (long)blockIdx.z * bsB;

    f32x4 acc[4][4];
#pragma unroll
    for (int i = 0; i < 4; ++i)
#pragma unroll
        for (int j = 0; j < 4; ++j) acc[i][j] = f32x4{0.f, 0.f, 0.f, 0.f};

    int jj, cc; swz_src(l, jj, cc);
    const int slot = swz_slot(l & 15, l >> 4);     // lane-const read slot

    const __bf16* Ag = A + (size_t)(m0 + w * 16 + jj) * K + cc * 8;
    const __bf16* Bg = B + (size_t)(n0 + w * 16 + jj) * K + cc * 8;
    char* AsB = (char*)As + w * 1024;
    char* BsB = (char*)Bs + w * 1024;

    for (int k0 = 0; k0 < K; k0 += BK) {
        GLOAD_LDS16(Ag + k0,                 AsB);
        GLOAD_LDS16(Ag + k0 + (size_t)64*K,  AsB + 4096);
        GLOAD_LDS16(Bg + k0,                 BsB);
        GLOAD_LDS16(Bg + k0 + (size_t)64*K,  BsB + 4096);
        __syncthreads();
        bf16x8 ar[4], br[4];
#pragma unroll
        for (int t = 0; t < 4; ++t) {
            ar[t] = *(const bf16x8*)(As + (wm*64 + t*16) * BK + slot * 8);
            br[t] = *(const bf16x8*)(Bs + (wn*64 + t*16) * BK + slot * 8);
        }
#pragma unroll
        for (int ti = 0; ti < 4; ++ti)
#pragma unroll
            for (int tj = 0; tj < 4; ++tj)
                acc[ti][tj] = __builtin_amdgcn_mfma_f32_16x16x32_bf16(
                    ar[ti], br[tj], acc[ti][tj], 0, 0, 0);
        __syncthreads();
    }

    const long cb = (long)blockIdx.z * bsC;
#pragma unroll
    for (int ti = 0; ti < 4; ++ti) {
#pragma unroll
        for (int r = 0; r < 4; ++r) {
            int m = m0 + wm*64 + ti*16 + (l >> 4)*4 + r;
            float bv = (EPI == 2 || EPI == 4) ? bias[m] : 0.f;
#pragma unroll
            for (int tj = 0; tj < 4; ++tj) {
                int n = n0 + wn*64 + tj*16 + (l & 15);
                float v = acc[ti][tj][r];
                if (EPI == 1) v += bias[n];
                if (EPI == 2 || EPI == 4) v += bv;
                if (EPI == 4) {
                    float rs = resid[(long)blockIdx.z * bsR + (size_t)m * N + n];
                    ((float*)Cv)[cb + (size_t)m * N + n] = v + rs;
                } else {
                    ((__bf16*)Cv)[cb + (size_t)m * N + n] = (__bf16)v;
                }
            }
        }
    }
}

// ---------------------------------------------------------------------------
// Flash attention (swizzled LDS + DPP softmax). One block = 64 q-rows.
// ---------------------------------------------------------------------------
#define PSTR 88   // P row stride (elems): 176 B -> full 8-group spread (free)

__global__ __launch_bounds__(256, 1) void flash_attn(
    const __bf16* __restrict__ Qt, const __bf16* __restrict__ Kt,
    const __bf16* __restrict__ Vb, __bf16* __restrict__ Ot)
{
    __shared__ __align__(16) __bf16 Ks[16 * 64 * 32];   // [kc][j:64][k:32] 64 KB
    __shared__ __align__(16) __bf16 Vs[2 * 512 * 32];   // [jc][c:512][j:32] 64 KB
    __shared__ __align__(16) __bf16 Ps[64 * PSTR];      // 11 KB
    __shared__ float scl[64];
    __shared__ float lnv[64];

    const int tid = threadIdx.x;
    const int l = tid & 63, w = tid >> 6;
    const int b = blockIdx.x >> 6;
    const int i0 = (blockIdx.x & 63) * 64;
    const size_t bb = (size_t)b * CL;
    const float alpha = 0.044194173824159216f;  // 1/sqrt(512)

    int jj, cc; swz_src(l, jj, cc);
    const int slot = swz_slot(l & 15, l >> 4);

    // Q fragments: wave w owns q-rows [i0+w*16, i0+w*16+16)
    bf16x8 Qf[16];
    {
        const __bf16* Qg = Qt + bb + (size_t)(i0 + w*16 + (l & 15)) * CCH + (l >> 4) * 8;
#pragma unroll
        for (int kc = 0; kc < 16; ++kc) Qf[kc] = *(const bf16x8*)(Qg + kc * 32);
    }

    f32x4 Oacc[4][8];
#pragma unroll
    for (int mi = 0; mi < 4; ++mi)
#pragma unroll
        for (int ni = 0; ni < 8; ++ni) Oacc[mi][ni] = f32x4{0.f, 0.f, 0.f, 0.f};
    float m_r[4], l_r[4];
#pragma unroll
    for (int r = 0; r < 4; ++r) { m_r[r] = -1e30f; l_r[r] = 0.f; }

    const __bf16* Kb = Kt + bb;
    const __bf16* Vg = Vb + bb;

    // K staging: 16 sub-chunks [64][32]; wave w stages kc = {w, w+4, w+8, w+12}
    auto stageK = [&](int j0) {
#pragma unroll
        for (int q = 0; q < 4; ++q) {
            int kc = q * 4 + w;
#pragma unroll
            for (int p = 0; p < 4; ++p) {
                const __bf16* src = Kb + (size_t)(j0 + p*16 + jj) * CCH + kc*32 + cc*8;
                GLOAD_LDS16(src, (char*)Ks + kc*4096 + p*1024);
            }
        }
    };
    // V staging: [jc][512][32]; wave w stages c-rows [w*128, w*128+128)
    auto stageV = [&](int j0) {
#pragma unroll
        for (int jc = 0; jc < 2; ++jc)
#pragma unroll
            for (int p = 0; p < 8; ++p) {
                const __bf16* src = Vg + (size_t)(w*128 + p*16 + jj) * LL + j0 + jc*32 + cc*8;
                GLOAD_LDS16(src, (char*)Vs + jc*32768 + (w*128 + p*16)*64);
            }
    };

    stageK(0);
    for (int t = 0; t < 64; ++t) {
        __syncthreads();             // K(t) staged (drain); PV(t-1) done
        stageV(t * 64);              // overlaps S-compute; drains at next barrier

        // S = Q . K^T  (wave's 16 rows x 64 j)
        f32x4 S[4];
#pragma unroll
        for (int tj = 0; tj < 4; ++tj) S[tj] = f32x4{0.f, 0.f, 0.f, 0.f};
#pragma unroll
        for (int kc = 0; kc < 16; ++kc) {
#pragma unroll
            for (int tj = 0; tj < 4; ++tj) {
                bf16x8 kf = *(const bf16x8*)(Ks + kc*2048 + tj*512 + slot*8);
                S[tj] = __builtin_amdgcn_mfma_f32_16x16x32_bf16(Qf[kc], kf, S[tj], 0, 0, 0);
            }
        }

        // online softmax; C-layout: row = w*16 + (l>>4)*4 + r, col = tj*16 + (l&15)
#pragma unroll
        for (int r = 0; r < 4; ++r) {
            float mt = -1e30f;
#pragma unroll
            for (int tj = 0; tj < 4; ++tj) { S[tj][r] *= alpha; mt = fmaxf(mt, S[tj][r]); }
            mt = red_max16(mt);
            float mn = fmaxf(m_r[r], mt);
            float a = __expf(m_r[r] - mn);
            m_r[r] = mn;
            int row = w*16 + (l >> 4)*4 + r;
            float rs = 0.f;
#pragma unroll
            for (int tj = 0; tj < 4; ++tj) {
                float p = __expf(S[tj][r] - mn);
                rs += p;
                Ps[row * PSTR + tj*16 + (l & 15)] = (__bf16)p;
            }
            rs = red_sum16(rs);
            l_r[r] = l_r[r] * a + rs;
            if ((l & 15) == 0) scl[row] = a;
        }

        __syncthreads();             // P + scl visible; V(t) staged (drain)
        if (t < 63) stageK((t + 1) * 64);   // overlaps PV; drains at loop-top barrier

        // rescale O by per-row alpha
#pragma unroll
        for (int mi = 0; mi < 4; ++mi)
#pragma unroll
            for (int r = 0; r < 4; ++r) {
                float s = scl[mi*16 + (l >> 4)*4 + r];
#pragma unroll
                for (int ni = 0; ni < 8; ++ni) Oacc[mi][ni][r] *= s;
            }

        // O += P . V^T   (M=64 i, N=512 c; wave owns c-slice [w*128, w*128+128))
#pragma unroll
        for (int jc = 0; jc < 2; ++jc) {
            bf16x8 pa[4];
#pragma unroll
            for (int mi = 0; mi < 4; ++mi)
                pa[mi] = *(const bf16x8*)(Ps + (mi*16 + (l & 15)) * PSTR + jc*32 + (l >> 4)*8);
#pragma unroll
            for (int ni = 0; ni < 8; ++ni) {
                bf16x8 vf = *(const bf16x8*)(Vs + jc*16384 + (w*128 + ni*16)*32 + slot*8);
#pragma unroll
                for (int mi = 0; mi < 4; ++mi)
                    Oacc[mi][ni] = __builtin_amdgcn_mfma_f32_16x16x32_bf16(pa[mi], vf, Oacc[mi][ni], 0, 0, 0);
            }
        }
    }

    // epilogue: O /= l, store Ot[i][c] bf16
    if ((l & 15) == 0) {
#pragma unroll
        for (int r = 0; r < 4; ++r) lnv[w*16 + (l >> 4)*4 + r] = 1.f / l_r[r];
    }
    __syncthreads();
#pragma unroll
    for (int mi = 0; mi < 4; ++mi) {
#pragma unroll
        for (int r = 0; r < 4; ++r) {
            int i = i0 + mi*16 + (l >> 4)*4 + r;
            float inv = lnv[mi*16 + (l >> 4)*4 + r];
#pragma unroll
            for (int ni = 0; ni < 8; ++ni) {
                int c = w*128 + ni*16 + (l & 15);
                Ot[bb + (size_t)i * CCH + c] = (__bf16)(Oacc[mi][ni][r] * inv);
            }
        }
    }
}

// ---------------------------------------------------------------------------
extern "C" void kernel_launch(void* const* d_in, const int* in_sizes, int n_in,
                              void* d_out, int out_size, void* d_ws, size_t ws_size,
                              hipStream_t stream) {
    const float* x   = (const float*)d_in[0];
    const float* gnw = (const float*)d_in[1];
    const float* gnb = (const float*)d_in[2];
    const float* wq  = (const float*)d_in[3];
    const float* bq  = (const float*)d_in[4];
    const float* wk  = (const float*)d_in[5];
    const float* bk  = (const float*)d_in[6];
    const float* wv  = (const float*)d_in[7];
    const float* bv  = (const float*)d_in[8];
    const float* wo  = (const float*)d_in[9];
    const float* bo  = (const float*)d_in[10];
    float* out = (float*)d_out;

    __bf16* wsb = (__bf16*)d_ws;
    const size_t NCL = (size_t)NB * CL;
    __bf16* Ht = wsb;
    __bf16* Qt = Ht + NCL;
    __bf16* Kt = Qt + NCL;
    __bf16* Vb = Kt + NCL;
    __bf16* Ot = Vb + NCL;
    __bf16* Wb = Ot + NCL;
    float* stats = (float*)(Wb + (size_t)4 * CCH * CCH);
    __bf16* wqb = Wb;
    __bf16* wkb = Wb + (size_t)CCH * CCH;
    __bf16* wvb = Wb + (size_t)2 * CCH * CCH;
    __bf16* wob = Wb + (size_t)3 * CCH * CCH;

    tobf16<<<256, 256, 0, stream>>>(wq, wqb, CCH * CCH);
    tobf16<<<256, 256, 0, stream>>>(wk, wkb, CCH * CCH);
    tobf16<<<256, 256, 0, stream>>>(wv, wvb, CCH * CCH);
    tobf16<<<256, 256, 0, stream>>>(wo, wob, CCH * CCH);

    gn_stats<<<NB * GRP, 1024, 0, stream>>>(x, stats);
    gn_norm_t<<<dim3(LL / 64, CCH / 64, NB), 256, 0, stream>>>(x, gnw, gnb, stats, Ht);

    gemm_nt<1><<<dim3(CCH / 128, LL / 128, NB), 256, 0, stream>>>(
        Ht, wqb, Qt, LL, CCH, CCH, CL, 0, CL, 0, bq, nullptr, 1.f);
    gemm_nt<1><<<dim3(CCH / 128, LL / 128, NB), 256, 0, stream>>>(
        Ht, wkb, Kt, LL, CCH, CCH, CL, 0, CL, 0, bk, nullptr, 1.f);
    gemm_nt<2><<<dim3(LL / 128, CCH / 128, NB), 256, 0, stream>>>(
        wvb, Ht, Vb, CCH, LL, CCH, 0, CL, CL, 0, bv, nullptr, 1.f);

    flash_attn<<<dim3(NB * (LL / 64)), 256, 0, stream>>>(Qt, Kt, Vb, Ot);

    gemm_nt<4><<<dim3(LL / 128, CCH / 128, NB), 256, 0, stream>>>(
        wob, Ot, (void*)out, CCH, LL, CCH, 0, CL, CL, CL, bo, x, 1.f);
}

// Round 5
// 427.207 us; speedup vs baseline: 6.4374x; 1.1019x over previous
//
#include <hip/hip_runtime.h>
#include <math.h>

#define NB   4
#define CCH  512
#define LL   4096
#define GRP  32
#define CPG  16
#define CL   (CCH*LL)
#define EPSV 1e-5f

typedef __bf16 bf16x8 __attribute__((ext_vector_type(8)));
typedef float  f32x4  __attribute__((ext_vector_type(4)));

#define GLOAD_LDS16(g, l) __builtin_amdgcn_global_load_lds( \
    (const __attribute__((address_space(1))) void*)(g),     \
    (__attribute__((address_space(3))) void*)(l), 16, 0, 0)

// ---------------------------------------------------------------------------
// XOR-swizzle for 16-row x 64B LDS tiles staged via global_load_lds
// (verified correct round 3/4; read slot is lane-constant).
// ---------------------------------------------------------------------------
__device__ __forceinline__ int swz_slot(int row, int q) {
    return (4 * row + (q ^ (row & 3))) ^ (((row >> 2) & 1) << 2);
}
__device__ __forceinline__ void swz_src(int l, int& jj, int& cc) {
    jj = ((l >> 3) << 1) | (((l >> 2) ^ (l >> 4)) & 1);
    cc = (l & 3) ^ (jj & 3);
}

// DPP 16-lane reductions — VALU-speed (no LDS).
#define DPPF(x, ctrl) __builtin_bit_cast(float, \
    __builtin_amdgcn_update_dpp(0, __builtin_bit_cast(int, (x)), (ctrl), 0xf, 0xf, false))
__device__ __forceinline__ float red_max16(float x) {
    x = fmaxf(x, DPPF(x, 0xB1)); x = fmaxf(x, DPPF(x, 0x4E));
    x = fmaxf(x, DPPF(x, 0x124)); x = fmaxf(x, DPPF(x, 0x128));
    return x;
}
__device__ __forceinline__ float red_sum16(float x) {
    x += DPPF(x, 0xB1); x += DPPF(x, 0x4E);
    x += DPPF(x, 0x124); x += DPPF(x, 0x128);
    return x;
}

// ---------------------------------------------------------------------------
// GroupNorm pass 1: per (n,g) mean/rstd.
// ---------------------------------------------------------------------------
__global__ __launch_bounds__(1024) void gn_stats(const float* __restrict__ x,
                                                 float* __restrict__ stats) {
    int n = blockIdx.x >> 5, g = blockIdx.x & 31;
    size_t base = ((size_t)n * CCH + (size_t)g * CPG) * LL;
    const float4* xp = (const float4*)(x + base);
    const int NV = CPG * LL / 4;
    int tid = threadIdx.x;
    float s1 = 0.f, s2 = 0.f;
    for (int i = tid; i < NV; i += 1024) {
        float4 v = xp[i];
        s1 += v.x + v.y + v.z + v.w;
        s2 += v.x*v.x + v.y*v.y + v.z*v.z + v.w*v.w;
    }
    __shared__ float red[32];
    for (int o = 32; o; o >>= 1) { s1 += __shfl_down(s1, o); s2 += __shfl_down(s2, o); }
    int lane = tid & 63, w = tid >> 6;
    if (!lane) { red[w] = s1; red[16 + w] = s2; }
    __syncthreads();
    if (tid == 0) {
        float a = 0.f, b = 0.f;
        for (int i = 0; i < 16; ++i) { a += red[i]; b += red[16 + i]; }
        const float inv_n = 1.f / (float)(CPG * LL);
        float mean = a * inv_n;
        float var  = b * inv_n - mean * mean;
        stats[blockIdx.x * 2]     = mean;
        stats[blockIdx.x * 2 + 1] = rsqrtf(var + EPSV);
    }
}

// ---------------------------------------------------------------------------
// GroupNorm pass 2 + transpose: x [C,L] fp32 -> Ht [L,C] bf16.
// ---------------------------------------------------------------------------
__global__ __launch_bounds__(256) void gn_norm_t(const float* __restrict__ x,
    const float* __restrict__ gamma, const float* __restrict__ beta,
    const float* __restrict__ stats, __bf16* __restrict__ Ht) {
    __shared__ float T[64][65];
    int n = blockIdx.z, c0 = blockIdx.y * 64, l0 = blockIdx.x * 64;
    int tid = threadIdx.x;
    int lx = tid & 63, py = tid >> 6;
    const float* xb = x + (size_t)n * CL;
#pragma unroll
    for (int p = 0; p < 16; ++p) {
        int cl = p * 4 + py;
        int c = c0 + cl;
        int g = c >> 4;
        float mean = stats[(n * GRP + g) * 2];
        float rstd = stats[(n * GRP + g) * 2 + 1];
        float sc = gamma[c] * rstd, bi = beta[c] - mean * sc;
        float v = xb[(size_t)c * LL + l0 + lx];
        T[lx][cl] = v * sc + bi;
    }
    __syncthreads();
    __bf16* hb = Ht + (size_t)n * CL;
#pragma unroll
    for (int p = 0; p < 16; ++p) {
        int ll = p * 4 + py;
        hb[(size_t)(l0 + ll) * CCH + c0 + lx] = (__bf16)T[ll][lx];
    }
}

// ---------------------------------------------------------------------------
__global__ __launch_bounds__(256) void tobf16(const float* __restrict__ src,
                                              __bf16* __restrict__ dst, int n) {
    int i = (blockIdx.x * 256 + threadIdx.x) * 4;
    if (i < n) {
        float4 v = *(const float4*)(src + i);
        dst[i]   = (__bf16)v.x; dst[i+1] = (__bf16)v.y;
        dst[i+2] = (__bf16)v.z; dst[i+3] = (__bf16)v.w;
    }
}

// ---------------------------------------------------------------------------
// bf16 MFMA GEMM, NT form, swizzled LDS (unchanged, verified).
// EPI: 1 +bias[n]->bf16, 2 +bias[m]->bf16, 4 +bias[m]+resid->fp32
// ---------------------------------------------------------------------------
#define BM 128
#define BN 128
#define BK 32

template<int EPI>
__global__ __launch_bounds__(256) void gemm_nt(
    const __bf16* __restrict__ A, const __bf16* __restrict__ B,
    void* __restrict__ Cv, int M, int N, int K,
    long bsA, long bsB, long bsC, long bsR,
    const float* __restrict__ bias, const float* __restrict__ resid, float alpha)
{
    __shared__ __align__(16) __bf16 As[BM * BK];
    __shared__ __align__(16) __bf16 Bs[BN * BK];
    const int tid = threadIdx.x;
    const int l = tid & 63, w = tid >> 6;
    const int wm = w >> 1, wn = w & 1;
    const int m0 = blockIdx.y * BM, n0 = blockIdx.x * BN;
    A += (long)blockIdx.z * bsA;
    B += (long)blockIdx.z * bsB;

    f32x4 acc[4][4];
#pragma unroll
    for (int i = 0; i < 4; ++i)
#pragma unroll
        for (int j = 0; j < 4; ++j) acc[i][j] = f32x4{0.f, 0.f, 0.f, 0.f};

    int jj, cc; swz_src(l, jj, cc);
    const int slot = swz_slot(l & 15, l >> 4);

    const __bf16* Ag = A + (size_t)(m0 + w * 16 + jj) * K + cc * 8;
    const __bf16* Bg = B + (size_t)(n0 + w * 16 + jj) * K + cc * 8;
    char* AsB = (char*)As + w * 1024;
    char* BsB = (char*)Bs + w * 1024;

    for (int k0 = 0; k0 < K; k0 += BK) {
        GLOAD_LDS16(Ag + k0,                 AsB);
        GLOAD_LDS16(Ag + k0 + (size_t)64*K,  AsB + 4096);
        GLOAD_LDS16(Bg + k0,                 BsB);
        GLOAD_LDS16(Bg + k0 + (size_t)64*K,  BsB + 4096);
        __syncthreads();
        bf16x8 ar[4], br[4];
#pragma unroll
        for (int t = 0; t < 4; ++t) {
            ar[t] = *(const bf16x8*)(As + (wm*64 + t*16) * BK + slot * 8);
            br[t] = *(const bf16x8*)(Bs + (wn*64 + t*16) * BK + slot * 8);
        }
#pragma unroll
        for (int ti = 0; ti < 4; ++ti)
#pragma unroll
            for (int tj = 0; tj < 4; ++tj)
                acc[ti][tj] = __builtin_amdgcn_mfma_f32_16x16x32_bf16(
                    ar[ti], br[tj], acc[ti][tj], 0, 0, 0);
        __syncthreads();
    }

    const long cb = (long)blockIdx.z * bsC;
#pragma unroll
    for (int ti = 0; ti < 4; ++ti) {
#pragma unroll
        for (int r = 0; r < 4; ++r) {
            int m = m0 + wm*64 + ti*16 + (l >> 4)*4 + r;
            float bv = (EPI == 2 || EPI == 4) ? bias[m] : 0.f;
#pragma unroll
            for (int tj = 0; tj < 4; ++tj) {
                int n = n0 + wn*64 + tj*16 + (l & 15);
                float v = acc[ti][tj][r];
                if (EPI == 1) v += bias[n];
                if (EPI == 2 || EPI == 4) v += bv;
                if (EPI == 4) {
                    float rs = resid[(long)blockIdx.z * bsR + (size_t)m * N + n];
                    ((float*)Cv)[cb + (size_t)m * N + n] = v + rs;
                } else {
                    ((__bf16*)Cv)[cb + (size_t)m * N + n] = (__bf16)v;
                }
            }
        }
    }
}

// ---------------------------------------------------------------------------
// Flash attention, 8 waves (512 thr): wave = (wi rows-16, kh k-half).
// S-phase: each wave accumulates its k-half (8 kc); kh=1 writes fp32 partial
// to Sm; kh=0 merges + softmax; PV: wave owns c-slice of 64 (Oacc 64 VGPR).
// 2 waves/SIMD (launch_bounds 512,2) for latency overlap.
// ---------------------------------------------------------------------------
#define PSTR 88

__global__ __launch_bounds__(512, 2) void flash_attn(
    const __bf16* __restrict__ Qt, const __bf16* __restrict__ Kt,
    const __bf16* __restrict__ Vb, __bf16* __restrict__ Ot)
{
    __shared__ __align__(16) __bf16 Ks[16 * 64 * 32];   // [kc][j:64][k:32] 64 KB
    __shared__ __align__(16) __bf16 Vs[2 * 512 * 32];   // [jc][c:512][j:32] 64 KB
    __shared__ __align__(16) float  Sm[64 * 68];        // S k-half merge, 17 KB
    __shared__ __align__(16) __bf16 Ps[64 * PSTR];      // 11 KB
    __shared__ float scl[64];
    __shared__ float lnv[64];

    const int tid = threadIdx.x;
    const int l = tid & 63, w = tid >> 6;
    const int wi = w & 3, kh = w >> 2;
    const int g = l >> 4, c = l & 15;
    const int b = blockIdx.x >> 6;
    const int i0 = (blockIdx.x & 63) * 64;
    const size_t bb = (size_t)b * CL;
    const float alpha = 0.044194173824159216f;  // 1/sqrt(512)

    int jj, cc; swz_src(l, jj, cc);
    const int slot = swz_slot(c, g);

    // Q fragments: wave (wi,kh) owns rows [i0+wi*16, +16), k-half kh*256
    bf16x8 Qf[8];
    {
        const __bf16* Qg = Qt + bb + (size_t)(i0 + wi*16 + c) * CCH + kh*256 + g*8;
#pragma unroll
        for (int kc = 0; kc < 8; ++kc) Qf[kc] = *(const bf16x8*)(Qg + kc * 32);
    }

    f32x4 Oacc[4][4];
#pragma unroll
    for (int mi = 0; mi < 4; ++mi)
#pragma unroll
        for (int ni = 0; ni < 4; ++ni) Oacc[mi][ni] = f32x4{0.f, 0.f, 0.f, 0.f};
    float m_r[4], l_r[4];
#pragma unroll
    for (int r = 0; r < 4; ++r) { m_r[r] = -1e30f; l_r[r] = 0.f; }

    const __bf16* Kb = Kt + bb;
    const __bf16* Vg = Vb + bb;

    // K staging: wave stages kc = {w, w+8} (8 instrs)
    auto stageK = [&](int j0) {
#pragma unroll
        for (int q = 0; q < 2; ++q) {
            int kc = q * 8 + w;
#pragma unroll
            for (int p = 0; p < 4; ++p) {
                const __bf16* src = Kb + (size_t)(j0 + p*16 + jj) * CCH + kc*32 + cc*8;
                GLOAD_LDS16(src, (char*)Ks + kc*4096 + p*1024);
            }
        }
    };
    // V staging: wave stages c-rows [w*64, +64) (8 instrs)
    auto stageV = [&](int j0) {
#pragma unroll
        for (int jc = 0; jc < 2; ++jc)
#pragma unroll
            for (int p = 0; p < 4; ++p) {
                const __bf16* src = Vg + (size_t)(w*64 + p*16 + jj) * LL + j0 + jc*32 + cc*8;
                GLOAD_LDS16(src, (char*)Vs + jc*32768 + (w*64 + p*16)*64);
            }
    };

    stageK(0);
    for (int t = 0; t < 64; ++t) {
        __syncthreads();             // B1: K(t) staged; prior PV done
        stageV(t * 64);

        // S partial over this wave's k-half (8 kc)
        f32x4 S[4];
#pragma unroll
        for (int tj = 0; tj < 4; ++tj) S[tj] = f32x4{0.f, 0.f, 0.f, 0.f};
#pragma unroll
        for (int kc = 0; kc < 8; ++kc) {
#pragma unroll
            for (int tj = 0; tj < 4; ++tj) {
                bf16x8 kf = *(const bf16x8*)(Ks + (kh*8 + kc)*2048 + tj*512 + slot*8);
                S[tj] = __builtin_amdgcn_mfma_f32_16x16x32_bf16(Qf[kc], kf, S[tj], 0, 0, 0);
            }
        }

        if (kh) {  // publish k-half partial
#pragma unroll
            for (int tj = 0; tj < 4; ++tj)
#pragma unroll
                for (int r = 0; r < 4; ++r)
                    Sm[(wi*16 + g*4 + r)*68 + tj*16 + c] = S[tj][r];
        }
        __syncthreads();             // B2: Sm visible; Ks(t) reads done

        if (!kh) {
            // merge + online softmax (rows wi*16 + g*4 + r)
#pragma unroll
            for (int r = 0; r < 4; ++r) {
                float mt = -1e30f;
#pragma unroll
                for (int tj = 0; tj < 4; ++tj) {
                    S[tj][r] = (S[tj][r] + Sm[(wi*16 + g*4 + r)*68 + tj*16 + c]) * alpha;
                    mt = fmaxf(mt, S[tj][r]);
                }
                mt = red_max16(mt);
                float mn = fmaxf(m_r[r], mt);
                float a = __expf(m_r[r] - mn);
                m_r[r] = mn;
                int row = wi*16 + g*4 + r;
                float rs = 0.f;
#pragma unroll
                for (int tj = 0; tj < 4; ++tj) {
                    float p = __expf(S[tj][r] - mn);
                    rs += p;
                    Ps[row * PSTR + tj*16 + c] = (__bf16)p;
                }
                rs = red_sum16(rs);
                l_r[r] = l_r[r] * a + rs;
                if (c == 0) scl[row] = a;
            }
        } else {
            if (t < 63) stageK((t + 1) * 64);   // prefetch during softmax
        }
        __syncthreads();             // B3: Ps/scl visible; V(t) staged
        if (t < 63 && !kh) stageK((t + 1) * 64);

        // rescale O (all 64 rows, this wave's c-slice)
#pragma unroll
        for (int mi = 0; mi < 4; ++mi)
#pragma unroll
            for (int r = 0; r < 4; ++r) {
                float s = scl[mi*16 + g*4 + r];
#pragma unroll
                for (int ni = 0; ni < 4; ++ni) Oacc[mi][ni][r] *= s;
            }

        // O += P . V^T  (all rows, c-slice [w*64, +64))
#pragma unroll
        for (int jc = 0; jc < 2; ++jc) {
            bf16x8 pa[4];
#pragma unroll
            for (int mi = 0; mi < 4; ++mi)
                pa[mi] = *(const bf16x8*)(Ps + (mi*16 + c) * PSTR + jc*32 + g*8);
#pragma unroll
            for (int ni = 0; ni < 4; ++ni) {
                bf16x8 vf = *(const bf16x8*)(Vs + jc*16384 + (w*64 + ni*16)*32 + slot*8);
#pragma unroll
                for (int mi = 0; mi < 4; ++mi)
                    Oacc[mi][ni] = __builtin_amdgcn_mfma_f32_16x16x32_bf16(pa[mi], vf, Oacc[mi][ni], 0, 0, 0);
            }
        }
    }

    if (!kh && c == 0) {
#pragma unroll
        for (int r = 0; r < 4; ++r) lnv[wi*16 + g*4 + r] = 1.f / l_r[r];
    }
    __syncthreads();
#pragma unroll
    for (int mi = 0; mi < 4; ++mi) {
#pragma unroll
        for (int r = 0; r < 4; ++r) {
            int row = mi*16 + g*4 + r;
            float inv = lnv[row];
#pragma unroll
            for (int ni = 0; ni < 4; ++ni) {
                int col = w*64 + ni*16 + c;
                Ot[bb + (size_t)(i0 + row) * CCH + col] = (__bf16)(Oacc[mi][ni][r] * inv);
            }
        }
    }
}

// ---------------------------------------------------------------------------
extern "C" void kernel_launch(void* const* d_in, const int* in_sizes, int n_in,
                              void* d_out, int out_size, void* d_ws, size_t ws_size,
                              hipStream_t stream) {
    const float* x   = (const float*)d_in[0];
    const float* gnw = (const float*)d_in[1];
    const float* gnb = (const float*)d_in[2];
    const float* wq  = (const float*)d_in[3];
    const float* bq  = (const float*)d_in[4];
    const float* wk  = (const float*)d_in[5];
    const float* bk  = (const float*)d_in[6];
    const float* wv  = (const float*)d_in[7];
    const float* bv  = (const float*)d_in[8];
    const float* wo  = (const float*)d_in[9];
    const float* bo  = (const float*)d_in[10];
    float* out = (float*)d_out;

    __bf16* wsb = (__bf16*)d_ws;
    const size_t NCL = (size_t)NB * CL;
    __bf16* Ht = wsb;
    __bf16* Qt = Ht + NCL;
    __bf16* Kt = Qt + NCL;
    __bf16* Vb = Kt + NCL;
    __bf16* Ot = Vb + NCL;
    __bf16* Wb = Ot + NCL;
    float* stats = (float*)(Wb + (size_t)4 * CCH * CCH);
    __bf16* wqb = Wb;
    __bf16* wkb = Wb + (size_t)CCH * CCH;
    __bf16* wvb = Wb + (size_t)2 * CCH * CCH;
    __bf16* wob = Wb + (size_t)3 * CCH * CCH;

    tobf16<<<256, 256, 0, stream>>>(wq, wqb, CCH * CCH);
    tobf16<<<256, 256, 0, stream>>>(wk, wkb, CCH * CCH);
    tobf16<<<256, 256, 0, stream>>>(wv, wvb, CCH * CCH);
    tobf16<<<256, 256, 0, stream>>>(wo, wob, CCH * CCH);

    gn_stats<<<NB * GRP, 1024, 0, stream>>>(x, stats);
    gn_norm_t<<<dim3(LL / 64, CCH / 64, NB), 256, 0, stream>>>(x, gnw, gnb, stats, Ht);

    gemm_nt<1><<<dim3(CCH / 128, LL / 128, NB), 256, 0, stream>>>(
        Ht, wqb, Qt, LL, CCH, CCH, CL, 0, CL, 0, bq, nullptr, 1.f);
    gemm_nt<1><<<dim3(CCH / 128, LL / 128, NB), 256, 0, stream>>>(
        Ht, wkb, Kt, LL, CCH, CCH, CL, 0, CL, 0, bk, nullptr, 1.f);
    gemm_nt<2><<<dim3(LL / 128, CCH / 128, NB), 256, 0, stream>>>(
        wvb, Ht, Vb, CCH, LL, CCH, 0, CL, CL, 0, bv, nullptr, 1.f);

    flash_attn<<<dim3(NB * (LL / 64)), 512, 0, stream>>>(Qt, Kt, Vb, Ot);

    gemm_nt<4><<<dim3(LL / 128, CCH / 128, NB), 256, 0, stream>>>(
        wob, Ot, (void*)out, CCH, LL, CCH, 0, CL, CL, CL, bo, x, 1.f);
}